// Round 13
// baseline (1355.920 us; speedup 1.0000x reference)
//
#include <hip/hip_runtime.h>
#include <hip/hip_bf16.h>

typedef short short8 __attribute__((ext_vector_type(8)));
typedef float f32x4 __attribute__((ext_vector_type(4)));
typedef unsigned short ushort_t;

#define SEQ 192
#define D_IN 156
#define HE 1024
#define HD 512
#define ZD 300
#define NB 64

// ---- barrier region: 12 groups x 32 WGs x 128B lines (monotonic counters) ----
#define BAR_BYTES 49152

// ---- ws byte offsets ----
// enc h: u32(2bf16), layout [dir][parity][bt(4)][chunk(32)][row(16)][q(16)]
// dec h1/h2: u32, layout [parity][bt(4)][chunk(16)][row(16)][q(16)]
#define XB_OFF   BAR_BYTES                      // bf16 x padded [192][64][160]
#define ONES_OFF (XB_OFF + SEQ*NB*160*2)        // bf16 ones [64][160]
#define OTF_OFF  (ONES_OFF + NB*160*2)          // f32 prev-out [64][160]
#define HE32_OFF (OTF_OFF + NB*160*4)           // enc h: 2 dir x 65536 u32
#define H132_OFF (HE32_OFF + 2*2*32768*4)       // dec h1: 2 x 16384 u32
#define H232_OFF (H132_OFF + 2*16384*4)         // dec h2: 2 x 16384 u32
#define CF_OFF   (H232_OFF + 2*16384*4)         // f32 c_f [64][1024]
#define CB_OFF   (CF_OFF + NB*HE*4)             // f32 c_b [64][1024]

#define OUT_ZMU  (NB*SEQ*D_IN)
#define OUT_ZVAR (OUT_ZMU + NB*ZD)

// ---------------- threefry2x32 (JAX-compatible, 20 rounds) ----------------
__host__ __device__ inline void threefry2x32(unsigned k0, unsigned k1,
                                             unsigned x0, unsigned x1,
                                             unsigned* o0, unsigned* o1) {
  unsigned ks0 = k0, ks1 = k1, ks2 = 0x1BD11BDAu ^ k0 ^ k1;
  x0 += ks0; x1 += ks1;
#define TF_RND(r) { x0 += x1; x1 = (x1 << (r)) | (x1 >> (32 - (r))); x1 ^= x0; }
  TF_RND(13) TF_RND(15) TF_RND(26) TF_RND(6)
  x0 += ks1; x1 += ks2 + 1u;
  TF_RND(17) TF_RND(29) TF_RND(16) TF_RND(24)
  x0 += ks2; x1 += ks0 + 2u;
  TF_RND(13) TF_RND(15) TF_RND(26) TF_RND(6)
  x0 += ks0; x1 += ks1 + 3u;
  TF_RND(17) TF_RND(29) TF_RND(16) TF_RND(24)
  x0 += ks1; x1 += ks2 + 4u;
  TF_RND(13) TF_RND(15) TF_RND(26) TF_RND(6)
  x0 += ks2; x1 += ks0 + 5u;
#undef TF_RND
  *o0 = x0; *o1 = x1;
}

__device__ __forceinline__ float tf_mask(unsigned k0, unsigned k1, unsigned idx,
                                         float keep, float scale) {
  unsigned o0, o1;
  threefry2x32(k0, k1, 0u, idx, &o0, &o1);
  unsigned bits = o0 ^ o1;
  float u = __uint_as_float(0x3f800000u | (bits >> 9)) - 1.0f;
  return (u < keep) ? scale : 0.0f;
}

__device__ __forceinline__ float sigf(float x) { return 1.0f / (1.0f + expf(-x)); }

__device__ __forceinline__ ushort_t f2bf(float f) {  // RNE float->bf16
  unsigned u = __float_as_uint(f);
  return (ushort_t)((u + 0x7fffu + ((u >> 16) & 1u)) >> 16);
}

#define MFMA(a,b,c) __builtin_amdgcn_mfma_f32_16x16x32_bf16((a),(b),(c),0,0,0)

// agent-scope relaxed store: write-through past L1/L2 to LLC (proven round 3)
__device__ __forceinline__ void ast(unsigned* p, unsigned v) {
  __hip_atomic_store(p, v, __ATOMIC_RELAXED, __HIP_MEMORY_SCOPE_AGENT);
}

// Coherent quad-load: 4 dwordx4 from 4 addresses, ONE waitcnt. sc0 sc1 bypass
// L1/L2 and read LLC (where ast stores land). "=&v" early-clobber mandatory.
__device__ __forceinline__ void cldq(const unsigned* p0, const unsigned* p1,
                                     const unsigned* p2, const unsigned* p3,
                                     uint4* o0, uint4* o1, uint4* o2, uint4* o3) {
  asm volatile(
    "global_load_dwordx4 %0, %4, off sc0 sc1\n\t"
    "global_load_dwordx4 %1, %5, off sc0 sc1\n\t"
    "global_load_dwordx4 %2, %6, off sc0 sc1\n\t"
    "global_load_dwordx4 %3, %7, off sc0 sc1\n\t"
    "s_waitcnt vmcnt(0)"
    : "=&v"(*o0), "=&v"(*o1), "=&v"(*o2), "=&v"(*o3)
    : "v"(p0), "v"(p1), "v"(p2), "v"(p3)
    : "memory");
}

// 8-address coherent load, one waitcnt (enc 64KB staging).
__device__ __forceinline__ void cld8p(const unsigned* p0, const unsigned* p1,
                                      const unsigned* p2, const unsigned* p3,
                                      const unsigned* p4, const unsigned* p5,
                                      const unsigned* p6, const unsigned* p7,
                                      uint4* o0, uint4* o1, uint4* o2, uint4* o3,
                                      uint4* o4, uint4* o5, uint4* o6, uint4* o7) {
  asm volatile(
    "global_load_dwordx4 %0, %8, off sc0 sc1\n\t"
    "global_load_dwordx4 %1, %9, off sc0 sc1\n\t"
    "global_load_dwordx4 %2, %10, off sc0 sc1\n\t"
    "global_load_dwordx4 %3, %11, off sc0 sc1\n\t"
    "global_load_dwordx4 %4, %12, off sc0 sc1\n\t"
    "global_load_dwordx4 %5, %13, off sc0 sc1\n\t"
    "global_load_dwordx4 %6, %14, off sc0 sc1\n\t"
    "global_load_dwordx4 %7, %15, off sc0 sc1\n\t"
    "s_waitcnt vmcnt(0)"
    : "=&v"(*o0), "=&v"(*o1), "=&v"(*o2), "=&v"(*o3),
      "=&v"(*o4), "=&v"(*o5), "=&v"(*o6), "=&v"(*o7)
    : "v"(p0), "v"(p1), "v"(p2), "v"(p3), "v"(p4), "v"(p5), "v"(p6), "v"(p7)
    : "memory");
}

__device__ __forceinline__ void cldf2(const float* p, float4* a, float4* b) {
  asm volatile(
    "global_load_dwordx4 %0, %2, off sc0 sc1\n\t"
    "global_load_dwordx4 %1, %2, off offset:16 sc0 sc1\n\t"
    "s_waitcnt vmcnt(0)"
    : "=&v"(*a), "=&v"(*b) : "v"(p) : "memory");
}

// ---------------- RMW-free per-group device barrier, FENCE-FREE ----------------
__device__ __forceinline__ void gbar3(int* bar, int grp, int idx, int target) {
  __syncthreads();
  if (threadIdx.x == 0) {
    asm volatile("s_waitcnt vmcnt(0) lgkmcnt(0)" ::: "memory");
    __hip_atomic_store(bar + (grp * 32 + idx) * 32, target,
                       __ATOMIC_RELAXED, __HIP_MEMORY_SCOPE_AGENT);
  }
  if (threadIdx.x < 32) {
    while (__hip_atomic_load(bar + (grp * 32 + (int)threadIdx.x) * 32,
                             __ATOMIC_RELAXED, __HIP_MEMORY_SCOPE_AGENT) < target) {}
  }
  __syncthreads();
}

// ---------------- prep: x -> bf16 padded [t][b][160]; ones row ----------------
__global__ __launch_bounds__(256) void prep_kernel(const float* __restrict__ x, char* wsb) {
  const int t = blockIdx.x;
  ushort_t* xb = (ushort_t*)(wsb + XB_OFF) + (size_t)t * NB * 160;
  for (int i = threadIdx.x; i < NB * 160; i += 256) {
    int b = i / 160, d = i - b * 160;
    xb[i] = (d < D_IN) ? f2bf(x[((size_t)b * SEQ + t) * D_IN + d]) : (ushort_t)0;
  }
  if (t == 0) {
    ushort_t* on = (ushort_t*)(wsb + ONES_OFF);
    for (int i = threadIdx.x; i < NB * 160; i += 256) {
      int d = i - (i / 160) * 160;
      on[i] = (d < D_IN) ? (ushort_t)0x3F80 : (ushort_t)0;
    }
  }
}

// LDS h-tile padding: 64B payload rows stored at 80B stride (20 u32).
// chunk stride = 16 rows * 80B = 1280B (320 u32). Read banks: lane i ->
// (20i + 4hi) mod 32 = exact 2-way aliasing = conflict-free (m136).

// ---------------- encoder body: 128 WGs (dir x bth x dp), 2 bt per WG ----------------
__device__ __forceinline__ void enc_body(
    int wg, const float* __restrict__ WihF, const float* __restrict__ WhhF,
    const float* __restrict__ bihF, const float* __restrict__ bhhF,
    const float* __restrict__ WihB, const float* __restrict__ WhhB,
    const float* __restrict__ bihB, const float* __restrict__ bhhB,
    char* wsb, int* bar, unsigned* hS, float (*gLDS4)[8][16][17],
    float (*sbias)[32]) {
  const int dir = wg >> 6;
  const int bth = (wg >> 5) & 1;
  const int dp  = wg & 31;
  const int grp = dir * 2 + bth;
  const int tid = threadIdx.x;
  const int w = tid >> 6, l = tid & 63;
  const int dtL = w >> 2, gate = w & 3;
  const int wrow = dp * 32 + dtL * 16 + (l & 15);
  const int grow = gate * HE + wrow;
  const int kseg = (l >> 4) * 8;

  const float* Whh = dir ? WhhB : WhhF;
  const float* Wih = dir ? WihB : WihF;
  const float* bih = dir ? bihB : bihF;
  const float* bhh = dir ? bhhB : bhhF;

  short8 wreg[37];  // register-resident bf16 B-fragments
#pragma unroll
  for (int c = 0; c < 32; ++c) {
    const float* p = Whh + (size_t)grow * HE + c * 32 + kseg;
    short8 v;
#pragma unroll
    for (int j = 0; j < 8; ++j) v[j] = (short)f2bf(p[j]);
    wreg[c] = v;
  }
#pragma unroll
  for (int c = 0; c < 5; ++c) {
    short8 v;
#pragma unroll
    for (int j = 0; j < 8; ++j) {
      int k = c * 32 + kseg + j;
      v[j] = (k < D_IN) ? (short)f2bf(Wih[(size_t)grow * D_IN + k]) : (short)0;
    }
    wreg[32 + c] = v;
  }

  const ushort_t* xb = (const ushort_t*)(wsb + XB_OFF);
  unsigned* hD32 = (unsigned*)(wsb + HE32_OFF) + (size_t)dir * 65536;  // [p][bt][c][r][q]
  float* cS = (float*)(wsb + (dir ? CB_OFF : CF_OFF));

  if (tid < 128) {
    int g = tid >> 5, dd = tid & 31;
    int gr = g * HE + dp * 32 + dd;
    sbias[g][dd] = bih[gr] + bhh[gr];
  }
  // padded LDS staging base: chunk(tid>>6)*320 + row*20 + col
  const int prow = (tid & 63) >> 2;
  const int pbase = (tid >> 6) * 320 + prow * 20 + (tid & 3) * 4;
  // finisher: 512 threads, one cell each: (btl, fb, dim-pair fdp)
  const int fbtl = tid >> 8;
  const int fb = (tid >> 4) & 15;
  const int fdp = tid & 15;
  const int fbt = bth * 2 + fbtl;
  float ca = 0.f, cb2 = 0.f;
  __syncthreads();

  for (int t = 0; t < SEQ; ++t) {
    const int ts = dir ? (SEQ - 1 - t) : t;
    if (t > 0) {  // stage BOTH bt tiles (64KB) in one batched LLC round-trip
      const unsigned* sp = hD32 + (size_t)(t & 1) * 32768 + bth * 16384 + tid * 4;
      uint4 a0, a1, a2, a3, a4, a5, a6, a7;
      cld8p(sp, sp + 2048, sp + 4096, sp + 6144,
            sp + 8192, sp + 10240, sp + 12288, sp + 14336,
            &a0, &a1, &a2, &a3, &a4, &a5, &a6, &a7);
      *(uint4*)&hS[pbase]            = a0;
      *(uint4*)&hS[pbase + 2560]     = a1;
      *(uint4*)&hS[pbase + 2 * 2560] = a2;
      *(uint4*)&hS[pbase + 3 * 2560] = a3;
      *(uint4*)&hS[pbase + 4 * 2560] = a4;
      *(uint4*)&hS[pbase + 5 * 2560] = a5;
      *(uint4*)&hS[pbase + 6 * 2560] = a6;
      *(uint4*)&hS[pbase + 7 * 2560] = a7;
    }
    __syncthreads();
#pragma unroll
    for (int btl = 0; btl < 2; ++btl) {
      const int arow = (bth * 2 + btl) * 16 + (l & 15);
      f32x4 acc0 = {0.f, 0.f, 0.f, 0.f}, acc1 = {0.f, 0.f, 0.f, 0.f};
      const ushort_t* xp = xb + (size_t)ts * NB * 160 + arow * 160 + kseg;
#pragma unroll
      for (int c = 0; c < 5; ++c) {  // x: plain loads, L1/L2-cached
        short8 f = *(const short8*)(const void*)(xp + c * 32);
        if (c & 1) acc1 = MFMA(f, wreg[32 + c], acc1);
        else       acc0 = MFMA(f, wreg[32 + c], acc0);
      }
      if (t > 0) {
        const char* hb = (const char*)hS + btl * 40960 + (l & 15) * 80 + (l >> 4) * 16;
#pragma unroll
        for (int c = 0; c < 32; ++c) {  // padded rows: conflict-free ds_read_b128
          short8 f = *(const short8*)(hb + c * 1280);
          if (c & 1) acc1 = MFMA(f, wreg[c], acc1);
          else       acc0 = MFMA(f, wreg[c], acc0);
        }
      }
      f32x4 acc = acc0 + acc1;
#pragma unroll
      for (int r = 0; r < 4; ++r)
        gLDS4[btl][w][(l >> 4) * 4 + r][l & 15] = acc[r];
    }
    __syncthreads();
    {  // finisher: one (bt, row, dim-pair) cell per thread
      float hv[2];
#pragma unroll
      for (int j = 0; j < 2; ++j) {
        int d = 2 * fdp + j;
        int fdt = d >> 4, fd = d & 15;
        float gi = gLDS4[fbtl][fdt * 4 + 0][fb][fd] + sbias[0][d];
        float gf = gLDS4[fbtl][fdt * 4 + 1][fb][fd] + sbias[1][d];
        float gg = gLDS4[fbtl][fdt * 4 + 2][fb][fd] + sbias[2][d];
        float go = gLDS4[fbtl][fdt * 4 + 3][fb][fd] + sbias[3][d];
        float& cc = j ? cb2 : ca;
        float ci = (t == 0) ? 0.f : cc;
        cc = sigf(gf) * ci + sigf(gi) * tanhf(gg);
        hv[j] = sigf(go) * tanhf(cc);
        if (t == SEQ - 1) cS[(size_t)(fbt * 16 + fb) * HE + dp * 32 + d] = cc;
      }
      unsigned pk = (unsigned)f2bf(hv[0]) | ((unsigned)f2bf(hv[1]) << 16);
      ast(hD32 + (size_t)((t + 1) & 1) * 32768 + ((fbt * 32 + dp) * 16 + fb) * 16 + fdp, pk);
    }
    if (t < SEQ - 1) gbar3(bar, grp, dp, t + 1);
  }
}

// ---------------- decoder body (round-11/12 proven, padded LDS) ----------------
__device__ __forceinline__ void dec_body(
    int wg, const float* __restrict__ Wih1, const float* __restrict__ Whh1,
    const float* __restrict__ bih1, const float* __restrict__ bhh1,
    const float* __restrict__ Wih2, const float* __restrict__ Whh2,
    const float* __restrict__ bih2, const float* __restrict__ bhh2,
    const float* __restrict__ Wout, const float* __restrict__ bout,
    const float* __restrict__ blc,
    char* wsb, int* bar, float* __restrict__ dout,
    unsigned mk1a, unsigned mk1b, unsigned mk2a, unsigned mk2b,
    unsigned* hS, float (*gLDS)[16][17], float (*sb1)[16], float (*sb2)[16]) {
  const int bt = wg >> 5;
  const int dt = wg & 31;
  const int d0 = dt * 16;
  const int tid = threadIdx.x;
  const int w = tid >> 6, l = tid & 63;
  const int kseg = (l >> 4) * 8;
  const bool isC1 = (w < 4);
  const int gate = w & 3;
  const int grow = gate * HD + d0 + (l & 15);
  const bool hasOut = (w == 0) && (dt < 10);
  const int orow = d0 + (l & 15);

  short8 wreg[37];
  if (isC1) {
#pragma unroll
    for (int c = 0; c < 5; ++c) {
      short8 v;
#pragma unroll
      for (int j = 0; j < 8; ++j) {
        int k = c * 32 + kseg + j;
        v[j] = (k < D_IN) ? (short)f2bf(Wih1[(size_t)grow * D_IN + k]) : (short)0;
      }
      wreg[c] = v;
    }
#pragma unroll
    for (int c = 0; c < 16; ++c) {
      const float* p = Whh1 + (size_t)grow * HD + c * 32 + kseg;
      short8 v;
#pragma unroll
      for (int j = 0; j < 8; ++j) v[j] = (short)f2bf(p[j]);
      wreg[5 + c] = v;
    }
    if (hasOut) {
#pragma unroll
      for (int c = 0; c < 16; ++c) {
        short8 v;
        if (orow < D_IN) {
          const float* p = Wout + (size_t)orow * HD + c * 32 + kseg;
#pragma unroll
          for (int j = 0; j < 8; ++j) v[j] = (short)f2bf(p[j]);
        } else {
#pragma unroll
          for (int j = 0; j < 8; ++j) v[j] = 0;
        }
        wreg[21 + c] = v;
      }
    }
  } else {
#pragma unroll
    for (int c = 0; c < 16; ++c) {
      const float* p = Wih2 + (size_t)grow * HD + c * 32 + kseg;
      short8 v;
#pragma unroll
      for (int j = 0; j < 8; ++j) v[j] = (short)f2bf(p[j]);
      wreg[c] = v;
    }
#pragma unroll
    for (int c = 0; c < 16; ++c) {
      const float* p = Whh2 + (size_t)grow * HD + c * 32 + kseg;
      short8 v;
#pragma unroll
      for (int j = 0; j < 8; ++j) v[j] = (short)f2bf(p[j]);
      wreg[16 + c] = v;
    }
  }

  const ushort_t* xb = (const ushort_t*)(wsb + XB_OFF);
  const ushort_t* on = (const ushort_t*)(wsb + ONES_OFF);
  float* oTf = (float*)(wsb + OTF_OFF);
  unsigned* h1b = (unsigned*)(wsb + H132_OFF);  // [p][bt][c(16)][r(16)][q(16)]
  unsigned* h2b = (unsigned*)(wsb + H232_OFF);

  if (tid < 64) {
    int g = tid >> 4, dd = tid & 15; int gr = g * HD + d0 + dd;
    sb1[g][dd] = bih1[gr] + bhh1[gr];
  } else if (tid < 128) {
    int q = tid - 64; int g = q >> 4, dd = q & 15; int gr = g * HD + d0 + dd;
    sb2[g][dd] = bih2[gr] + bhh2[gr];
  }

  const int ffb = (tid & 127) >> 3;
  const int ffp = tid & 7;
  const int fbg = bt * 16 + ffb;
  float c1a = 0.f, c1b = 0.f, c2a = 0.f, c2b = 0.f;
  const float blcA = blc[d0 + 2 * ffp];
  const float blcB = blc[d0 + 2 * ffp + 1];
  const float bo = (hasOut && orow < D_IN) ? bout[orow] : 0.f;
  const int arow = bt * 16 + (l & 15);
  const int hstore = bt * 4096 + (((dt >> 1) * 16 + ffb) * 16 + (dt & 1) * 8 + ffp);
  // padded LDS staging base (tid<256 for T1, tid-256 for T2)
  const int ptid = tid & 255;
  const int pbase = (ptid >> 6) * 320 + ((ptid & 63) >> 2) * 20 + (ptid & 3) * 4;
  __syncthreads();

  int t1 = 0, t2 = 0, to = 0, phase = 0;
  while (to < SEQ) {
    const bool samp1 = (t1 > 0) && ((t1 & 7) == 0);
    const bool do1 = (t1 < SEQ) && (!samp1 || (to >= t1));
    const bool do2 = (t2 < t1);
    const bool doo = (to < t2);
    // ---- stage h1/h2 tiles into LDS (once per WG, padded rows) ----
    {
      const int p1 = do1 ? (t1 & 1) : ((t2 + 1) & 1);
      const int p2 = t2 & 1;
      if (tid < 256) {
        if ((do1 && t1 > 0) || do2) {
          const unsigned* sp = h1b + (size_t)p1 * 16384 + bt * 4096 + tid * 4;
          uint4 a0, a1, a2, a3;
          cldq(sp, sp + 1024, sp + 2048, sp + 3072, &a0, &a1, &a2, &a3);
          *(uint4*)&hS[pbase]            = a0;
          *(uint4*)&hS[pbase + 1280]     = a1;
          *(uint4*)&hS[pbase + 2 * 1280] = a2;
          *(uint4*)&hS[pbase + 3 * 1280] = a3;
        }
      } else if (tid < 512) {
        if ((do2 && t2 > 0) || doo) {
          const unsigned* sp = h2b + (size_t)p2 * 16384 + bt * 4096 + ptid * 4;
          uint4 a0, a1, a2, a3;
          cldq(sp, sp + 1024, sp + 2048, sp + 3072, &a0, &a1, &a2, &a3);
          *(uint4*)&hS[5120 + pbase]            = a0;
          *(uint4*)&hS[5120 + pbase + 1280]     = a1;
          *(uint4*)&hS[5120 + pbase + 2 * 1280] = a2;
          *(uint4*)&hS[5120 + pbase + 3 * 1280] = a3;
        }
      }
    }
    __syncthreads();
    const char* hbase = (const char*)hS + (l & 15) * 80 + (l >> 4) * 16;
    // ---- compute stage ----
    if (do1 && isC1) {
      f32x4 acc0 = {0.f,0.f,0.f,0.f}, acc1 = {0.f,0.f,0.f,0.f};
      if (t1 == 0) {
        const ushort_t* src = on + arow * 160 + kseg;
#pragma unroll
        for (int c = 0; c < 5; ++c) {
          short8 f = *(const short8*)(const void*)(src + c * 32);
          if (c & 1) acc1 = MFMA(f, wreg[c], acc1); else acc0 = MFMA(f, wreg[c], acc0);
        }
      } else if (samp1) {
#pragma unroll
        for (int c = 0; c < 5; ++c) {
          const float* pf = oTf + arow * 160 + c * 32 + kseg;
          float4 f0, f1;
          cldf2(pf, &f0, &f1);
          short8 v;
          v[0] = (short)f2bf(f0.x); v[1] = (short)f2bf(f0.y);
          v[2] = (short)f2bf(f0.z); v[3] = (short)f2bf(f0.w);
          v[4] = (short)f2bf(f1.x); v[5] = (short)f2bf(f1.y);
          v[6] = (short)f2bf(f1.z); v[7] = (short)f2bf(f1.w);
          if (c & 1) acc1 = MFMA(v, wreg[c], acc1); else acc0 = MFMA(v, wreg[c], acc0);
        }
      } else {
        const ushort_t* src = xb + (size_t)(t1 - 1) * NB * 160 + arow * 160 + kseg;
#pragma unroll
        for (int c = 0; c < 5; ++c) {
          short8 f = *(const short8*)(const void*)(src + c * 32);
          if (c & 1) acc1 = MFMA(f, wreg[c], acc1); else acc0 = MFMA(f, wreg[c], acc0);
        }
      }
      if (t1 > 0) {
#pragma unroll
        for (int c = 0; c < 16; ++c) {
          short8 f = *(const short8*)(hbase + c * 1280);
          if (c & 1) acc1 = MFMA(f, wreg[5 + c], acc1);
          else       acc0 = MFMA(f, wreg[5 + c], acc0);
        }
      }
      f32x4 acc = acc0 + acc1;
#pragma unroll
      for (int r = 0; r < 4; ++r)
        gLDS[w][(l >> 4) * 4 + r][l & 15] = acc[r];
    }
    if (do2 && !isC1) {
      f32x4 acc0 = {0.f,0.f,0.f,0.f}, acc1 = {0.f,0.f,0.f,0.f};
#pragma unroll
      for (int c = 0; c < 16; ++c) {        // h1(t2+1) from T1
        short8 f = *(const short8*)(hbase + c * 1280);
        if (c & 1) acc1 = MFMA(f, wreg[c], acc1);
        else       acc0 = MFMA(f, wreg[c], acc0);
      }
      if (t2 > 0) {
#pragma unroll
        for (int c = 0; c < 16; ++c) {      // h2(t2) from T2
          short8 f = *(const short8*)(hbase + 20480 + c * 1280);
          if (c & 1) acc1 = MFMA(f, wreg[16 + c], acc1);
          else       acc0 = MFMA(f, wreg[16 + c], acc0);
        }
      }
      f32x4 acc = acc0 + acc1;
#pragma unroll
      for (int r = 0; r < 4; ++r)
        gLDS[w][(l >> 4) * 4 + r][l & 15] = acc[r];
    }
    if (doo && hasOut) {
      f32x4 acc0 = {0.f,0.f,0.f,0.f}, acc1 = {0.f,0.f,0.f,0.f};
#pragma unroll
      for (int c = 0; c < 16; ++c) {        // h2(to+1) from T2
        short8 f = *(const short8*)(hbase + 20480 + c * 1280);
        if (c & 1) acc1 = MFMA(f, wreg[21 + c], acc1);
        else       acc0 = MFMA(f, wreg[21 + c], acc0);
      }
      f32x4 acc = acc0 + acc1;
      if (orow < D_IN) {
#pragma unroll
        for (int r = 0; r < 4; ++r) {
          int bg = bt * 16 + (l >> 4) * 4 + r;
          float v = sigf(acc[r] + bo);
          dout[(size_t)bg * (SEQ * D_IN) + to * D_IN + orow] = v;
          ast((unsigned*)(oTf + bg * 160 + orow), __float_as_uint(v));
        }
      }
    }
    __syncthreads();
    // ---- finisher stage ----
    if (do1 && tid < 128) {
      float hv[2];
#pragma unroll
      for (int j = 0; j < 2; ++j) {
        int d = 2 * ffp + j;
        float gi = gLDS[0][ffb][d] + sb1[0][d];
        float gf = gLDS[1][ffb][d] + sb1[1][d];
        float gg = gLDS[2][ffb][d] + sb1[2][d];
        float go = gLDS[3][ffb][d] + sb1[3][d];
        float& cc = j ? c1b : c1a;
        float cin = (t1 > 0 && (t1 & 31) == 0) ? cc : (j ? blcB : blcA);
        cc = sigf(gf) * cin + sigf(gi) * tanhf(gg);
        float h = sigf(go) * tanhf(cc);
        h *= tf_mask(mk1a, mk1b, (unsigned)((t1 * NB + fbg) * HD + d0 + d), 0.5f, 2.0f);
        hv[j] = h;
      }
      unsigned pk = (unsigned)f2bf(hv[0]) | ((unsigned)f2bf(hv[1]) << 16);
      ast(h1b + (size_t)((t1 + 1) & 1) * 16384 + hstore, pk);
    }
    if (do2 && tid >= 128 && tid < 256) {
      float hv[2];
#pragma unroll
      for (int j = 0; j < 2; ++j) {
        int d = 2 * ffp + j;
        float gi = gLDS[4][ffb][d] + sb2[0][d];
        float gf = gLDS[5][ffb][d] + sb2[1][d];
        float gg = gLDS[6][ffb][d] + sb2[2][d];
        float go = gLDS[7][ffb][d] + sb2[3][d];
        float& cc = j ? c2b : c2a;
        cc = sigf(gf) * cc + sigf(gi) * tanhf(gg);
        float h = sigf(go) * tanhf(cc);
        h *= tf_mask(mk2a, mk2b, (unsigned)((t2 * NB + fbg) * HD + d0 + d), 0.8f, 1.25f);
        hv[j] = h;
      }
      unsigned pk = (unsigned)f2bf(hv[0]) | ((unsigned)f2bf(hv[1]) << 16);
      ast(h2b + (size_t)((t2 + 1) & 1) * 16384 + hstore, pk);
    }
    t1 += do1; t2 += do2; to += doo;
    if (to < SEQ) gbar3(bar, 8 + bt, dt, phase + 1);
    ++phase;
  }
}

// ---------------- fused: 256 WGs (128 enc + 128 dec), 1 WG/CU co-resident ----------------
__global__ __launch_bounds__(512, 2) void fused_kernel(
    const float* __restrict__ WihF, const float* __restrict__ WhhF,
    const float* __restrict__ bihF, const float* __restrict__ bhhF,
    const float* __restrict__ WihB, const float* __restrict__ WhhB,
    const float* __restrict__ bihB, const float* __restrict__ bhhB,
    const float* __restrict__ Wih1, const float* __restrict__ Whh1,
    const float* __restrict__ bih1, const float* __restrict__ bhh1,
    const float* __restrict__ Wih2, const float* __restrict__ Whh2,
    const float* __restrict__ bih2, const float* __restrict__ bhh2,
    const float* __restrict__ Wout, const float* __restrict__ bout,
    const float* __restrict__ blc,
    char* wsb, int* bar, float* __restrict__ dout,
    unsigned mk1a, unsigned mk1b, unsigned mk2a, unsigned mk2b) {
  __shared__ unsigned hS[20480];            // 80KB padded (enc: 2x40960B; dec: T1+T2)
  __shared__ float gLDS4[2][8][16][17];     // padded rows (dec uses gLDS4[0])
  __shared__ float sbias[4][32];
  if (blockIdx.x < 128) {
    enc_body(blockIdx.x, WihF, WhhF, bihF, bhhF, WihB, WhhB, bihB, bhhB,
             wsb, bar, hS, gLDS4, sbias);
  } else {
    float (*sb1)[16] = (float(*)[16])(&sbias[0][0]);
    float (*sb2)[16] = sb1 + 4;
    dec_body(blockIdx.x - 128, Wih1, Whh1, bih1, bhh1, Wih2, Whh2, bih2, bhh2,
             Wout, bout, blc, wsb, bar, dout, mk1a, mk1b, mk2a, mk2b,
             hS, gLDS4[0], sb1, sb2);
  }
}

// ---------------- z head ----------------
__global__ __launch_bounds__(256) void z_kernel(
    const float* __restrict__ Wmu, const float* __restrict__ bmu,
    const float* __restrict__ Wvar, const float* __restrict__ bvar,
    const char* wsb, float* __restrict__ dout, unsigned ek0, unsigned ek1) {
  const int r = blockIdx.x;
  const int tid = threadIdx.x;
  __shared__ float fin[2 * HE];
  const float* cf = (const float*)(wsb + CF_OFF);
  const float* cb = (const float*)(wsb + CB_OFF);
  const float K7 = 0.7f, S7 = 1.0f / 0.7f;
  for (int q = tid; q < 2 * HE; q += 256) {
    int half = q >> 10, col = q & 1023;
    float cv = (r < 32) ? cf[(2 * r + half) * HE + col]
                        : cb[(2 * (r - 32) + half) * HE + col];
    fin[q] = cv * tf_mask(ek0, ek1, (unsigned)(r * 2048 + q), K7, S7);
  }
  __syncthreads();
  for (int z = tid; z < ZD; z += 256) {
    const float* wm = Wmu + (size_t)z * (2 * HE);
    const float* wv = Wvar + (size_t)z * (2 * HE);
    float am = 0.f, av = 0.f;
#pragma unroll 4
    for (int q = 0; q < 2 * HE; ++q) { float f = fin[q]; am += f * wm[q]; av += f * wv[q]; }
    dout[OUT_ZMU + r * ZD + z]  = am + bmu[z];
    dout[OUT_ZVAR + r * ZD + z] = av + bvar[z];
  }
}

extern "C" void kernel_launch(void* const* d_in, const int* in_sizes, int n_in,
                              void* d_out, int out_size, void* d_ws, size_t ws_size,
                              hipStream_t stream) {
  (void)in_sizes; (void)n_in; (void)out_size; (void)ws_size;
  const float* x    = (const float*)d_in[0];
  const float* WihF = (const float*)d_in[1];
  const float* WhhF = (const float*)d_in[2];
  const float* bihF = (const float*)d_in[3];
  const float* bhhF = (const float*)d_in[4];
  const float* WihB = (const float*)d_in[5];
  const float* WhhB = (const float*)d_in[6];
  const float* bihB = (const float*)d_in[7];
  const float* bhhB = (const float*)d_in[8];
  const float* Wmu  = (const float*)d_in[9];
  const float* bmu  = (const float*)d_in[10];
  const float* Wvar = (const float*)d_in[11];
  const float* bvar = (const float*)d_in[12];
  // d_in[13] = W_lc (dead: relu(0) @ W_lc.T == 0)
  const float* blc  = (const float*)d_in[14];
  const float* Wih1 = (const float*)d_in[15];
  const float* Whh1 = (const float*)d_in[16];
  const float* bih1 = (const float*)d_in[17];
  const float* bhh1 = (const float*)d_in[18];
  const float* Wih2 = (const float*)d_in[19];
  const float* Whh2 = (const float*)d_in[20];
  const float* bih2 = (const float*)d_in[21];
  const float* bhh2 = (const float*)d_in[22];
  const float* Wout = (const float*)d_in[23];
  const float* bout = (const float*)d_in[24];
  char* wsb = (char*)d_ws;
  int*  bar = (int*)d_ws;
  float* dout = (float*)d_out;

  hipMemsetAsync(d_ws, 0, BAR_BYTES, stream);

  unsigned e0, e1, m10, m11, m20, m21;
  threefry2x32(0u, 42u, 0u, 0u, &e0, &e1);    // enc_m key
  threefry2x32(0u, 42u, 0u, 1u, &m10, &m11);  // m1 key
  threefry2x32(0u, 42u, 0u, 2u, &m20, &m21);  // m2 key

  prep_kernel<<<SEQ, 256, 0, stream>>>(x, wsb);
  fused_kernel<<<256, 512, 0, stream>>>(WihF, WhhF, bihF, bhhF,
                                        WihB, WhhB, bihB, bhhB,
                                        Wih1, Whh1, bih1, bhh1,
                                        Wih2, Whh2, bih2, bhh2,
                                        Wout, bout, blc, wsb, bar, dout,
                                        m10, m11, m20, m21);
  z_kernel<<<64, 256, 0, stream>>>(Wmu, bmu, Wvar, bvar, wsb, dout, e0, e1);
}

// Round 14
// 1208.528 us; speedup vs baseline: 1.1220x; 1.1220x over previous
//
#include <hip/hip_runtime.h>
#include <hip/hip_bf16.h>

typedef short short8 __attribute__((ext_vector_type(8)));
typedef float f32x4 __attribute__((ext_vector_type(4)));
typedef unsigned short ushort_t;

#define SEQ 192
#define D_IN 156
#define HE 1024
#define HD 512
#define ZD 300
#define NB 64

// ---- barrier region: 12 groups x 32 WGs x 128B lines (monotonic counters) ----
#define BAR_BYTES 49152

// ---- ws byte offsets ----
// enc h: u32(2bf16), layout [dir][parity][bt(4)][chunk(32)][row(16)][q(16)]
// dec h1/h2: u32, layout [parity][bt(4)][chunk(16)][row(16)][q(16)]
#define XB_OFF   BAR_BYTES                      // bf16 x padded [192][64][160]
#define ONES_OFF (XB_OFF + SEQ*NB*160*2)        // bf16 ones [64][160]
#define OTF_OFF  (ONES_OFF + NB*160*2)          // f32 prev-out [64][160]
#define HE32_OFF (OTF_OFF + NB*160*4)           // enc h: 2 dir x 65536 u32
#define H132_OFF (HE32_OFF + 2*2*32768*4)       // dec h1: 2 x 16384 u32
#define H232_OFF (H132_OFF + 2*16384*4)         // dec h2: 2 x 16384 u32
#define CF_OFF   (H232_OFF + 2*16384*4)         // f32 c_f [64][1024]
#define CB_OFF   (CF_OFF + NB*HE*4)             // f32 c_b [64][1024]

#define OUT_ZMU  (NB*SEQ*D_IN)
#define OUT_ZVAR (OUT_ZMU + NB*ZD)

// ---------------- threefry2x32 (JAX-compatible, 20 rounds) ----------------
__host__ __device__ inline void threefry2x32(unsigned k0, unsigned k1,
                                             unsigned x0, unsigned x1,
                                             unsigned* o0, unsigned* o1) {
  unsigned ks0 = k0, ks1 = k1, ks2 = 0x1BD11BDAu ^ k0 ^ k1;
  x0 += ks0; x1 += ks1;
#define TF_RND(r) { x0 += x1; x1 = (x1 << (r)) | (x1 >> (32 - (r))); x1 ^= x0; }
  TF_RND(13) TF_RND(15) TF_RND(26) TF_RND(6)
  x0 += ks1; x1 += ks2 + 1u;
  TF_RND(17) TF_RND(29) TF_RND(16) TF_RND(24)
  x0 += ks2; x1 += ks0 + 2u;
  TF_RND(13) TF_RND(15) TF_RND(26) TF_RND(6)
  x0 += ks0; x1 += ks1 + 3u;
  TF_RND(17) TF_RND(29) TF_RND(16) TF_RND(24)
  x0 += ks1; x1 += ks2 + 4u;
  TF_RND(13) TF_RND(15) TF_RND(26) TF_RND(6)
  x0 += ks2; x1 += ks0 + 5u;
#undef TF_RND
  *o0 = x0; *o1 = x1;
}

__device__ __forceinline__ float tf_mask(unsigned k0, unsigned k1, unsigned idx,
                                         float keep, float scale) {
  unsigned o0, o1;
  threefry2x32(k0, k1, 0u, idx, &o0, &o1);
  unsigned bits = o0 ^ o1;
  float u = __uint_as_float(0x3f800000u | (bits >> 9)) - 1.0f;
  return (u < keep) ? scale : 0.0f;
}

__device__ __forceinline__ float sigf(float x) { return 1.0f / (1.0f + expf(-x)); }

__device__ __forceinline__ ushort_t f2bf(float f) {  // RNE float->bf16
  unsigned u = __float_as_uint(f);
  return (ushort_t)((u + 0x7fffu + ((u >> 16) & 1u)) >> 16);
}

#define MFMA(a,b,c) __builtin_amdgcn_mfma_f32_16x16x32_bf16((a),(b),(c),0,0,0)

// agent-scope relaxed store: write-through past L1/L2 to LLC (proven round 3)
__device__ __forceinline__ void ast(unsigned* p, unsigned v) {
  __hip_atomic_store(p, v, __ATOMIC_RELAXED, __HIP_MEMORY_SCOPE_AGENT);
}

// Coherent quad-load: 4 dwordx4 from 4 addresses, ONE waitcnt. sc0 sc1 bypass
// L1/L2 and read LLC (where ast stores land). "=&v" early-clobber mandatory.
__device__ __forceinline__ void cldq(const unsigned* p0, const unsigned* p1,
                                     const unsigned* p2, const unsigned* p3,
                                     uint4* o0, uint4* o1, uint4* o2, uint4* o3) {
  asm volatile(
    "global_load_dwordx4 %0, %4, off sc0 sc1\n\t"
    "global_load_dwordx4 %1, %5, off sc0 sc1\n\t"
    "global_load_dwordx4 %2, %6, off sc0 sc1\n\t"
    "global_load_dwordx4 %3, %7, off sc0 sc1\n\t"
    "s_waitcnt vmcnt(0)"
    : "=&v"(*o0), "=&v"(*o1), "=&v"(*o2), "=&v"(*o3)
    : "v"(p0), "v"(p1), "v"(p2), "v"(p3)
    : "memory");
}

// 8-address coherent load, one waitcnt (enc 64KB staging).
__device__ __forceinline__ void cld8p(const unsigned* p0, const unsigned* p1,
                                      const unsigned* p2, const unsigned* p3,
                                      const unsigned* p4, const unsigned* p5,
                                      const unsigned* p6, const unsigned* p7,
                                      uint4* o0, uint4* o1, uint4* o2, uint4* o3,
                                      uint4* o4, uint4* o5, uint4* o6, uint4* o7) {
  asm volatile(
    "global_load_dwordx4 %0, %8, off sc0 sc1\n\t"
    "global_load_dwordx4 %1, %9, off sc0 sc1\n\t"
    "global_load_dwordx4 %2, %10, off sc0 sc1\n\t"
    "global_load_dwordx4 %3, %11, off sc0 sc1\n\t"
    "global_load_dwordx4 %4, %12, off sc0 sc1\n\t"
    "global_load_dwordx4 %5, %13, off sc0 sc1\n\t"
    "global_load_dwordx4 %6, %14, off sc0 sc1\n\t"
    "global_load_dwordx4 %7, %15, off sc0 sc1\n\t"
    "s_waitcnt vmcnt(0)"
    : "=&v"(*o0), "=&v"(*o1), "=&v"(*o2), "=&v"(*o3),
      "=&v"(*o4), "=&v"(*o5), "=&v"(*o6), "=&v"(*o7)
    : "v"(p0), "v"(p1), "v"(p2), "v"(p3), "v"(p4), "v"(p5), "v"(p6), "v"(p7)
    : "memory");
}

__device__ __forceinline__ void cldf2(const float* p, float4* a, float4* b) {
  asm volatile(
    "global_load_dwordx4 %0, %2, off sc0 sc1\n\t"
    "global_load_dwordx4 %1, %2, off offset:16 sc0 sc1\n\t"
    "s_waitcnt vmcnt(0)"
    : "=&v"(*a), "=&v"(*b) : "v"(p) : "memory");
}

// ---------------- RMW-free per-group device barrier, FENCE-FREE ----------------
__device__ __forceinline__ void gbar3(int* bar, int grp, int idx, int target) {
  __syncthreads();
  if (threadIdx.x == 0) {
    asm volatile("s_waitcnt vmcnt(0) lgkmcnt(0)" ::: "memory");
    __hip_atomic_store(bar + (grp * 32 + idx) * 32, target,
                       __ATOMIC_RELAXED, __HIP_MEMORY_SCOPE_AGENT);
  }
  if (threadIdx.x < 32) {
    while (__hip_atomic_load(bar + (grp * 32 + (int)threadIdx.x) * 32,
                             __ATOMIC_RELAXED, __HIP_MEMORY_SCOPE_AGENT) < target) {}
  }
  __syncthreads();
}

// ---------------- prep: x -> bf16 padded [t][b][160]; ones row ----------------
__global__ __launch_bounds__(256) void prep_kernel(const float* __restrict__ x, char* wsb) {
  const int t = blockIdx.x;
  ushort_t* xb = (ushort_t*)(wsb + XB_OFF) + (size_t)t * NB * 160;
  for (int i = threadIdx.x; i < NB * 160; i += 256) {
    int b = i / 160, d = i - b * 160;
    xb[i] = (d < D_IN) ? f2bf(x[((size_t)b * SEQ + t) * D_IN + d]) : (ushort_t)0;
  }
  if (t == 0) {
    ushort_t* on = (ushort_t*)(wsb + ONES_OFF);
    for (int i = threadIdx.x; i < NB * 160; i += 256) {
      int d = i - (i / 160) * 160;
      on[i] = (d < D_IN) ? (ushort_t)0x3F80 : (ushort_t)0;
    }
  }
}

// ---------------- encoder body: 128 WGs (dir x bth x dp), 2 bt per WG ----------------
__device__ __forceinline__ void enc_body(
    int wg, const float* __restrict__ WihF, const float* __restrict__ WhhF,
    const float* __restrict__ bihF, const float* __restrict__ bhhF,
    const float* __restrict__ WihB, const float* __restrict__ WhhB,
    const float* __restrict__ bihB, const float* __restrict__ bhhB,
    char* wsb, int* bar, unsigned* hS, float (*gLDS4)[8][16][16],
    float (*sbias)[32]) {
  const int dir = wg >> 6;
  const int bth = (wg >> 5) & 1;
  const int dp  = wg & 31;
  const int grp = dir * 2 + bth;
  const int tid = threadIdx.x;
  const int w = tid >> 6, l = tid & 63;
  const int dtL = w >> 2, gate = w & 3;
  const int wrow = dp * 32 + dtL * 16 + (l & 15);
  const int grow = gate * HE + wrow;
  const int kseg = (l >> 4) * 8;

  const float* Whh = dir ? WhhB : WhhF;
  const float* Wih = dir ? WihB : WihF;
  const float* bih = dir ? bihB : bihF;
  const float* bhh = dir ? bhhB : bhhF;

  short8 wreg[37];  // register-resident bf16 B-fragments
#pragma unroll
  for (int c = 0; c < 32; ++c) {
    const float* p = Whh + (size_t)grow * HE + c * 32 + kseg;
    short8 v;
#pragma unroll
    for (int j = 0; j < 8; ++j) v[j] = (short)f2bf(p[j]);
    wreg[c] = v;
  }
#pragma unroll
  for (int c = 0; c < 5; ++c) {
    short8 v;
#pragma unroll
    for (int j = 0; j < 8; ++j) {
      int k = c * 32 + kseg + j;
      v[j] = (k < D_IN) ? (short)f2bf(Wih[(size_t)grow * D_IN + k]) : (short)0;
    }
    wreg[32 + c] = v;
  }

  const ushort_t* xb = (const ushort_t*)(wsb + XB_OFF);
  unsigned* hD32 = (unsigned*)(wsb + HE32_OFF) + (size_t)dir * 65536;  // [p][bt][c][r][q]
  float* cS = (float*)(wsb + (dir ? CB_OFF : CF_OFF));

  if (tid < 128) {
    int g = tid >> 5, dd = tid & 31;
    int gr = g * HE + dp * 32 + dd;
    sbias[g][dd] = bih[gr] + bhh[gr];
  }
  // finisher: 512 threads, one cell each: (btl, fb, dim-pair fdp)
  const int fbtl = tid >> 8;
  const int fb = (tid >> 4) & 15;
  const int fdp = tid & 15;
  const int fbt = bth * 2 + fbtl;
  float ca = 0.f, cb2 = 0.f;
  __syncthreads();

  for (int t = 0; t < SEQ; ++t) {
    const int ts = dir ? (SEQ - 1 - t) : t;
    if (t > 0) {  // stage BOTH bt tiles (64KB) in one batched LLC round-trip
      const unsigned* sp = hD32 + (size_t)(t & 1) * 32768 + bth * 16384 + tid * 4;
      uint4 a0, a1, a2, a3, a4, a5, a6, a7;
      cld8p(sp, sp + 2048, sp + 4096, sp + 6144,
            sp + 8192, sp + 10240, sp + 12288, sp + 14336,
            &a0, &a1, &a2, &a3, &a4, &a5, &a6, &a7);
      *(uint4*)&hS[tid * 4]         = a0;
      *(uint4*)&hS[tid * 4 + 2048]  = a1;
      *(uint4*)&hS[tid * 4 + 4096]  = a2;
      *(uint4*)&hS[tid * 4 + 6144]  = a3;
      *(uint4*)&hS[tid * 4 + 8192]  = a4;
      *(uint4*)&hS[tid * 4 + 10240] = a5;
      *(uint4*)&hS[tid * 4 + 12288] = a6;
      *(uint4*)&hS[tid * 4 + 14336] = a7;
    }
    __syncthreads();
#pragma unroll
    for (int btl = 0; btl < 2; ++btl) {
      const int arow = (bth * 2 + btl) * 16 + (l & 15);
      f32x4 acc0 = {0.f, 0.f, 0.f, 0.f}, acc1 = {0.f, 0.f, 0.f, 0.f};
      const ushort_t* xp = xb + (size_t)ts * NB * 160 + arow * 160 + kseg;
#pragma unroll
      for (int c = 0; c < 5; ++c) {  // x: plain loads, L1/L2-cached
        short8 f = *(const short8*)(const void*)(xp + c * 32);
        if (c & 1) acc1 = MFMA(f, wreg[32 + c], acc1);
        else       acc0 = MFMA(f, wreg[32 + c], acc0);
      }
      if (t > 0) {
        const char* hb = (const char*)hS + btl * 32768 + (l & 15) * 64 + (l >> 4) * 16;
#pragma unroll
        for (int c = 0; c < 32; ++c) {
          short8 f = *(const short8*)(hb + c * 1024);
          if (c & 1) acc1 = MFMA(f, wreg[c], acc1);
          else       acc0 = MFMA(f, wreg[c], acc0);
        }
      }
      f32x4 acc = acc0 + acc1;
#pragma unroll
      for (int r = 0; r < 4; ++r)
        gLDS4[btl][w][(l >> 4) * 4 + r][l & 15] = acc[r];
    }
    __syncthreads();
    {  // finisher: one (bt, row, dim-pair) cell per thread
      float hv[2];
#pragma unroll
      for (int j = 0; j < 2; ++j) {
        int d = 2 * fdp + j;
        int fdt = d >> 4, fd = d & 15;
        float gi = gLDS4[fbtl][fdt * 4 + 0][fb][fd] + sbias[0][d];
        float gf = gLDS4[fbtl][fdt * 4 + 1][fb][fd] + sbias[1][d];
        float gg = gLDS4[fbtl][fdt * 4 + 2][fb][fd] + sbias[2][d];
        float go = gLDS4[fbtl][fdt * 4 + 3][fb][fd] + sbias[3][d];
        float& cc = j ? cb2 : ca;
        float ci = (t == 0) ? 0.f : cc;
        cc = sigf(gf) * ci + sigf(gi) * tanhf(gg);
        hv[j] = sigf(go) * tanhf(cc);
        if (t == SEQ - 1) cS[(size_t)(fbt * 16 + fb) * HE + dp * 32 + d] = cc;
      }
      unsigned pk = (unsigned)f2bf(hv[0]) | ((unsigned)f2bf(hv[1]) << 16);
      ast(hD32 + (size_t)((t + 1) & 1) * 32768 + ((fbt * 32 + dp) * 16 + fb) * 16 + fdp, pk);
    }
    if (t < SEQ - 1) gbar3(bar, grp, dp, t + 1);
  }
}

// ---------------- decoder body (round-11/12 proven) ----------------
__device__ __forceinline__ void dec_body(
    int wg, const float* __restrict__ Wih1, const float* __restrict__ Whh1,
    const float* __restrict__ bih1, const float* __restrict__ bhh1,
    const float* __restrict__ Wih2, const float* __restrict__ Whh2,
    const float* __restrict__ bih2, const float* __restrict__ bhh2,
    const float* __restrict__ Wout, const float* __restrict__ bout,
    const float* __restrict__ blc,
    char* wsb, int* bar, float* __restrict__ dout,
    unsigned mk1a, unsigned mk1b, unsigned mk2a, unsigned mk2b,
    unsigned* hS, float (*gLDS)[16][16], float (*sb1)[16], float (*sb2)[16]) {
  const int bt = wg >> 5;
  const int dt = wg & 31;
  const int d0 = dt * 16;
  const int tid = threadIdx.x;
  const int w = tid >> 6, l = tid & 63;
  const int kseg = (l >> 4) * 8;
  const bool isC1 = (w < 4);
  const int gate = w & 3;
  const int grow = gate * HD + d0 + (l & 15);
  const bool hasOut = (w == 0) && (dt < 10);
  const int orow = d0 + (l & 15);

  short8 wreg[37];
  if (isC1) {
#pragma unroll
    for (int c = 0; c < 5; ++c) {
      short8 v;
#pragma unroll
      for (int j = 0; j < 8; ++j) {
        int k = c * 32 + kseg + j;
        v[j] = (k < D_IN) ? (short)f2bf(Wih1[(size_t)grow * D_IN + k]) : (short)0;
      }
      wreg[c] = v;
    }
#pragma unroll
    for (int c = 0; c < 16; ++c) {
      const float* p = Whh1 + (size_t)grow * HD + c * 32 + kseg;
      short8 v;
#pragma unroll
      for (int j = 0; j < 8; ++j) v[j] = (short)f2bf(p[j]);
      wreg[5 + c] = v;
    }
    if (hasOut) {
#pragma unroll
      for (int c = 0; c < 16; ++c) {
        short8 v;
        if (orow < D_IN) {
          const float* p = Wout + (size_t)orow * HD + c * 32 + kseg;
#pragma unroll
          for (int j = 0; j < 8; ++j) v[j] = (short)f2bf(p[j]);
        } else {
#pragma unroll
          for (int j = 0; j < 8; ++j) v[j] = 0;
        }
        wreg[21 + c] = v;
      }
    }
  } else {
#pragma unroll
    for (int c = 0; c < 16; ++c) {
      const float* p = Wih2 + (size_t)grow * HD + c * 32 + kseg;
      short8 v;
#pragma unroll
      for (int j = 0; j < 8; ++j) v[j] = (short)f2bf(p[j]);
      wreg[c] = v;
    }
#pragma unroll
    for (int c = 0; c < 16; ++c) {
      const float* p = Whh2 + (size_t)grow * HD + c * 32 + kseg;
      short8 v;
#pragma unroll
      for (int j = 0; j < 8; ++j) v[j] = (short)f2bf(p[j]);
      wreg[16 + c] = v;
    }
  }

  const ushort_t* xb = (const ushort_t*)(wsb + XB_OFF);
  const ushort_t* on = (const ushort_t*)(wsb + ONES_OFF);
  float* oTf = (float*)(wsb + OTF_OFF);
  unsigned* h1b = (unsigned*)(wsb + H132_OFF);  // [p][bt][c(16)][r(16)][q(16)]
  unsigned* h2b = (unsigned*)(wsb + H232_OFF);

  if (tid < 64) {
    int g = tid >> 4, dd = tid & 15; int gr = g * HD + d0 + dd;
    sb1[g][dd] = bih1[gr] + bhh1[gr];
  } else if (tid < 128) {
    int q = tid - 64; int g = q >> 4, dd = q & 15; int gr = g * HD + d0 + dd;
    sb2[g][dd] = bih2[gr] + bhh2[gr];
  }

  const int ffb = (tid & 127) >> 3;
  const int ffp = tid & 7;
  const int fbg = bt * 16 + ffb;
  float c1a = 0.f, c1b = 0.f, c2a = 0.f, c2b = 0.f;
  const float blcA = blc[d0 + 2 * ffp];
  const float blcB = blc[d0 + 2 * ffp + 1];
  const float bo = (hasOut && orow < D_IN) ? bout[orow] : 0.f;
  const int arow = bt * 16 + (l & 15);
  const int hstore = bt * 4096 + (((dt >> 1) * 16 + ffb) * 16 + (dt & 1) * 8 + ffp);
  __syncthreads();

  int t1 = 0, t2 = 0, to = 0, phase = 0;
  while (to < SEQ) {
    const bool samp1 = (t1 > 0) && ((t1 & 7) == 0);
    const bool do1 = (t1 < SEQ) && (!samp1 || (to >= t1));
    const bool do2 = (t2 < t1);
    const bool doo = (to < t2);
    // ---- stage h1/h2 tiles into LDS (once per WG) ----
    {
      const int p1 = do1 ? (t1 & 1) : ((t2 + 1) & 1);
      const int p2 = t2 & 1;
      if (tid < 256) {
        if ((do1 && t1 > 0) || do2) {
          const unsigned* sp = h1b + (size_t)p1 * 16384 + bt * 4096 + tid * 4;
          uint4 a0, a1, a2, a3;
          cldq(sp, sp + 1024, sp + 2048, sp + 3072, &a0, &a1, &a2, &a3);
          *(uint4*)&hS[tid * 4]        = a0;
          *(uint4*)&hS[tid * 4 + 1024] = a1;
          *(uint4*)&hS[tid * 4 + 2048] = a2;
          *(uint4*)&hS[tid * 4 + 3072] = a3;
        }
      } else if (tid < 512) {
        if ((do2 && t2 > 0) || doo) {
          const int td = tid - 256;
          const unsigned* sp = h2b + (size_t)p2 * 16384 + bt * 4096 + td * 4;
          uint4 a0, a1, a2, a3;
          cldq(sp, sp + 1024, sp + 2048, sp + 3072, &a0, &a1, &a2, &a3);
          *(uint4*)&hS[4096 + td * 4]        = a0;
          *(uint4*)&hS[4096 + td * 4 + 1024] = a1;
          *(uint4*)&hS[4096 + td * 4 + 2048] = a2;
          *(uint4*)&hS[4096 + td * 4 + 3072] = a3;
        }
      }
    }
    __syncthreads();
    const char* hbase = (const char*)hS + (l & 15) * 64 + (l >> 4) * 16;
    // ---- compute stage ----
    if (do1 && isC1) {
      f32x4 acc0 = {0.f,0.f,0.f,0.f}, acc1 = {0.f,0.f,0.f,0.f};
      if (t1 == 0) {
        const ushort_t* src = on + arow * 160 + kseg;
#pragma unroll
        for (int c = 0; c < 5; ++c) {
          short8 f = *(const short8*)(const void*)(src + c * 32);
          if (c & 1) acc1 = MFMA(f, wreg[c], acc1); else acc0 = MFMA(f, wreg[c], acc0);
        }
      } else if (samp1) {
#pragma unroll
        for (int c = 0; c < 5; ++c) {
          const float* pf = oTf + arow * 160 + c * 32 + kseg;
          float4 f0, f1;
          cldf2(pf, &f0, &f1);
          short8 v;
          v[0] = (short)f2bf(f0.x); v[1] = (short)f2bf(f0.y);
          v[2] = (short)f2bf(f0.z); v[3] = (short)f2bf(f0.w);
          v[4] = (short)f2bf(f1.x); v[5] = (short)f2bf(f1.y);
          v[6] = (short)f2bf(f1.z); v[7] = (short)f2bf(f1.w);
          if (c & 1) acc1 = MFMA(v, wreg[c], acc1); else acc0 = MFMA(v, wreg[c], acc0);
        }
      } else {
        const ushort_t* src = xb + (size_t)(t1 - 1) * NB * 160 + arow * 160 + kseg;
#pragma unroll
        for (int c = 0; c < 5; ++c) {
          short8 f = *(const short8*)(const void*)(src + c * 32);
          if (c & 1) acc1 = MFMA(f, wreg[c], acc1); else acc0 = MFMA(f, wreg[c], acc0);
        }
      }
      if (t1 > 0) {
#pragma unroll
        for (int c = 0; c < 16; ++c) {
          short8 f = *(const short8*)(hbase + c * 1024);
          if (c & 1) acc1 = MFMA(f, wreg[5 + c], acc1);
          else       acc0 = MFMA(f, wreg[5 + c], acc0);
        }
      }
      f32x4 acc = acc0 + acc1;
#pragma unroll
      for (int r = 0; r < 4; ++r)
        gLDS[w][(l >> 4) * 4 + r][l & 15] = acc[r];
    }
    if (do2 && !isC1) {
      f32x4 acc0 = {0.f,0.f,0.f,0.f}, acc1 = {0.f,0.f,0.f,0.f};
#pragma unroll
      for (int c = 0; c < 16; ++c) {        // h1(t2+1) from T1
        short8 f = *(const short8*)(hbase + c * 1024);
        if (c & 1) acc1 = MFMA(f, wreg[c], acc1);
        else       acc0 = MFMA(f, wreg[c], acc0);
      }
      if (t2 > 0) {
#pragma unroll
        for (int c = 0; c < 16; ++c) {      // h2(t2) from T2
          short8 f = *(const short8*)(hbase + 16384 + c * 1024);
          if (c & 1) acc1 = MFMA(f, wreg[16 + c], acc1);
          else       acc0 = MFMA(f, wreg[16 + c], acc0);
        }
      }
      f32x4 acc = acc0 + acc1;
#pragma unroll
      for (int r = 0; r < 4; ++r)
        gLDS[w][(l >> 4) * 4 + r][l & 15] = acc[r];
    }
    if (doo && hasOut) {
      f32x4 acc0 = {0.f,0.f,0.f,0.f}, acc1 = {0.f,0.f,0.f,0.f};
#pragma unroll
      for (int c = 0; c < 16; ++c) {        // h2(to+1) from T2
        short8 f = *(const short8*)(hbase + 16384 + c * 1024);
        if (c & 1) acc1 = MFMA(f, wreg[21 + c], acc1);
        else       acc0 = MFMA(f, wreg[21 + c], acc0);
      }
      f32x4 acc = acc0 + acc1;
      if (orow < D_IN) {
#pragma unroll
        for (int r = 0; r < 4; ++r) {
          int bg = bt * 16 + (l >> 4) * 4 + r;
          float v = sigf(acc[r] + bo);
          dout[(size_t)bg * (SEQ * D_IN) + to * D_IN + orow] = v;
          ast((unsigned*)(oTf + bg * 160 + orow), __float_as_uint(v));
        }
      }
    }
    __syncthreads();
    // ---- finisher stage ----
    if (do1 && tid < 128) {
      float hv[2];
#pragma unroll
      for (int j = 0; j < 2; ++j) {
        int d = 2 * ffp + j;
        float gi = gLDS[0][ffb][d] + sb1[0][d];
        float gf = gLDS[1][ffb][d] + sb1[1][d];
        float gg = gLDS[2][ffb][d] + sb1[2][d];
        float go = gLDS[3][ffb][d] + sb1[3][d];
        float& cc = j ? c1b : c1a;
        float cin = (t1 > 0 && (t1 & 31) == 0) ? cc : (j ? blcB : blcA);
        cc = sigf(gf) * cin + sigf(gi) * tanhf(gg);
        float h = sigf(go) * tanhf(cc);
        h *= tf_mask(mk1a, mk1b, (unsigned)((t1 * NB + fbg) * HD + d0 + d), 0.5f, 2.0f);
        hv[j] = h;
      }
      unsigned pk = (unsigned)f2bf(hv[0]) | ((unsigned)f2bf(hv[1]) << 16);
      ast(h1b + (size_t)((t1 + 1) & 1) * 16384 + hstore, pk);
    }
    if (do2 && tid >= 128 && tid < 256) {
      float hv[2];
#pragma unroll
      for (int j = 0; j < 2; ++j) {
        int d = 2 * ffp + j;
        float gi = gLDS[4][ffb][d] + sb2[0][d];
        float gf = gLDS[5][ffb][d] + sb2[1][d];
        float gg = gLDS[6][ffb][d] + sb2[2][d];
        float go = gLDS[7][ffb][d] + sb2[3][d];
        float& cc = j ? c2b : c2a;
        cc = sigf(gf) * cc + sigf(gi) * tanhf(gg);
        float h = sigf(go) * tanhf(cc);
        h *= tf_mask(mk2a, mk2b, (unsigned)((t2 * NB + fbg) * HD + d0 + d), 0.8f, 1.25f);
        hv[j] = h;
      }
      unsigned pk = (unsigned)f2bf(hv[0]) | ((unsigned)f2bf(hv[1]) << 16);
      ast(h2b + (size_t)((t2 + 1) & 1) * 16384 + hstore, pk);
    }
    t1 += do1; t2 += do2; to += doo;
    if (to < SEQ) gbar3(bar, 8 + bt, dt, phase + 1);
    ++phase;
  }
}

// ---------------- fused: 256 WGs (128 enc + 128 dec), 1 WG/CU co-resident ----------------
__global__ __launch_bounds__(512, 2) void fused_kernel(
    const float* __restrict__ WihF, const float* __restrict__ WhhF,
    const float* __restrict__ bihF, const float* __restrict__ bhhF,
    const float* __restrict__ WihB, const float* __restrict__ WhhB,
    const float* __restrict__ bihB, const float* __restrict__ bhhB,
    const float* __restrict__ Wih1, const float* __restrict__ Whh1,
    const float* __restrict__ bih1, const float* __restrict__ bhh1,
    const float* __restrict__ Wih2, const float* __restrict__ Whh2,
    const float* __restrict__ bih2, const float* __restrict__ bhh2,
    const float* __restrict__ Wout, const float* __restrict__ bout,
    const float* __restrict__ blc,
    char* wsb, int* bar, float* __restrict__ dout,
    unsigned mk1a, unsigned mk1b, unsigned mk2a, unsigned mk2b) {
  __shared__ unsigned hS[16384];          // 64KB (enc: 2 bt tiles; dec: T1+T2 in first 32KB)
  __shared__ float gLDS4[2][8][16][16];   // 16KB (dec uses gLDS4[0])
  __shared__ float sbias[4][32];          // 512B (dec: sb1/sb2 carved)
  if (blockIdx.x < 128) {
    enc_body(blockIdx.x, WihF, WhhF, bihF, bhhF, WihB, WhhB, bihB, bhhB,
             wsb, bar, hS, gLDS4, sbias);
  } else {
    float (*sb1)[16] = (float(*)[16])(&sbias[0][0]);
    float (*sb2)[16] = sb1 + 4;
    dec_body(blockIdx.x - 128, Wih1, Whh1, bih1, bhh1, Wih2, Whh2, bih2, bhh2,
             Wout, bout, blc, wsb, bar, dout, mk1a, mk1b, mk2a, mk2b,
             hS, gLDS4[0], sb1, sb2);
  }
}

// ---------------- z head: 192 blocks = 16 r-groups x 12 z-chunks of 25 ----------------
// Each block stages fin for 4 r rows in LDS; each Wmu/Wvar row is read by the
// 4 threads (same z, different r) -> L1 broadcast. Aggregate weight traffic
// 314MB -> 78MB, 3x block parallelism. Per-dot K order unchanged (bit-identical).
__global__ __launch_bounds__(128) void z_kernel(
    const float* __restrict__ Wmu, const float* __restrict__ bmu,
    const float* __restrict__ Wvar, const float* __restrict__ bvar,
    const char* wsb, float* __restrict__ dout, unsigned ek0, unsigned ek1) {
  const int rg = blockIdx.x / 12;   // 0..15
  const int zc = blockIdx.x % 12;   // 0..11
  const int tid = threadIdx.x;
  __shared__ float fin[4][2 * HE];
  const float* cf = (const float*)(wsb + CF_OFF);
  const float* cb = (const float*)(wsb + CB_OFF);
  const float K7 = 0.7f, S7 = 1.0f / 0.7f;
  for (int i = tid; i < 4 * 2 * HE; i += 128) {
    int rl = i >> 11, q = i & 2047;
    int rr = rg * 4 + rl;
    int half = q >> 10, col = q & 1023;
    float cv = (rr < 32) ? cf[(2 * rr + half) * HE + col]
                         : cb[(2 * (rr - 32) + half) * HE + col];
    fin[rl][q] = cv * tf_mask(ek0, ek1, (unsigned)(rr * 2048 + q), K7, S7);
  }
  __syncthreads();
  const int rl = tid >> 5;          // 0..3
  const int zs = tid & 31;
  if (zs < 25) {
    const int z = zc * 25 + zs;     // 12*25 = 300
    const int r = rg * 4 + rl;
    const float* wm = Wmu + (size_t)z * (2 * HE);
    const float* wv = Wvar + (size_t)z * (2 * HE);
    float am = 0.f, av = 0.f;
#pragma unroll 4
    for (int q = 0; q < 2 * HE; ++q) { float f = fin[rl][q]; am += f * wm[q]; av += f * wv[q]; }
    dout[OUT_ZMU + r * ZD + z]  = am + bmu[z];
    dout[OUT_ZVAR + r * ZD + z] = av + bvar[z];
  }
}

extern "C" void kernel_launch(void* const* d_in, const int* in_sizes, int n_in,
                              void* d_out, int out_size, void* d_ws, size_t ws_size,
                              hipStream_t stream) {
  (void)in_sizes; (void)n_in; (void)out_size; (void)ws_size;
  const float* x    = (const float*)d_in[0];
  const float* WihF = (const float*)d_in[1];
  const float* WhhF = (const float*)d_in[2];
  const float* bihF = (const float*)d_in[3];
  const float* bhhF = (const float*)d_in[4];
  const float* WihB = (const float*)d_in[5];
  const float* WhhB = (const float*)d_in[6];
  const float* bihB = (const float*)d_in[7];
  const float* bhhB = (const float*)d_in[8];
  const float* Wmu  = (const float*)d_in[9];
  const float* bmu  = (const float*)d_in[10];
  const float* Wvar = (const float*)d_in[11];
  const float* bvar = (const float*)d_in[12];
  // d_in[13] = W_lc (dead: relu(0) @ W_lc.T == 0)
  const float* blc  = (const float*)d_in[14];
  const float* Wih1 = (const float*)d_in[15];
  const float* Whh1 = (const float*)d_in[16];
  const float* bih1 = (const float*)d_in[17];
  const float* bhh1 = (const float*)d_in[18];
  const float* Wih2 = (const float*)d_in[19];
  const float* Whh2 = (const float*)d_in[20];
  const float* bih2 = (const float*)d_in[21];
  const float* bhh2 = (const float*)d_in[22];
  const float* Wout = (const float*)d_in[23];
  const float* bout = (const float*)d_in[24];
  char* wsb = (char*)d_ws;
  int*  bar = (int*)d_ws;
  float* dout = (float*)d_out;

  hipMemsetAsync(d_ws, 0, BAR_BYTES, stream);

  unsigned e0, e1, m10, m11, m20, m21;
  threefry2x32(0u, 42u, 0u, 0u, &e0, &e1);    // enc_m key
  threefry2x32(0u, 42u, 0u, 1u, &m10, &m11);  // m1 key
  threefry2x32(0u, 42u, 0u, 2u, &m20, &m21);  // m2 key

  prep_kernel<<<SEQ, 256, 0, stream>>>(x, wsb);
  fused_kernel<<<256, 512, 0, stream>>>(WihF, WhhF, bihF, bhhF,
                                        WihB, WhhB, bihB, bhhB,
                                        Wih1, Whh1, bih1, bhh1,
                                        Wih2, Whh2, bih2, bhh2,
                                        Wout, bout, blc, wsb, bar, dout,
                                        m10, m11, m20, m21);
  z_kernel<<<192, 128, 0, stream>>>(Wmu, bmu, Wvar, bvar, wsb, dout, e0, e1);
}